// Round 2
// baseline (214.035 us; speedup 1.0000x reference)
//
#include <hip/hip_runtime.h>
#include <hip/hip_bf16.h>

using u32 = unsigned int;
using u16 = unsigned short;

// Problem constants (match reference; E taken from in_sizes at runtime)
#define NGR   512     // graphs
#define NF    128     // edge features
#define GF    64      // global features
#define HID   64      // hidden
#define IN1   192     // GF + NF
#define SPLIT 8       // reduce blocks per graph

// counting-sort tiling
#define HT    256                 // threads for hist/scatter
#define ITEMS 10                  // edges per thread
#define EPB   (HT * ITEMS)        // 2560 edges per block

__global__ void zero_counts_kernel(u32* __restrict__ counts) {
    counts[threadIdx.x] = 0u;     // <<<1,512>>>
}

__global__ void hist_kernel(const int* __restrict__ ei0,
                            const int* __restrict__ batch,
                            u32* __restrict__ g_counts,
                            u16* __restrict__ seg, int E) {
    __shared__ u32 h[NGR];
    int tid = threadIdx.x;
    h[tid] = 0u; h[tid + 256] = 0u;
    __syncthreads();
    int base = blockIdx.x * EPB + tid;
#pragma unroll
    for (int i = 0; i < ITEMS; ++i) {
        int e = base + i * HT;
        if (e < E) {
            int s = batch[ei0[e]];
            seg[e] = (u16)s;                 // cache graph id for scatter pass
            atomicAdd(&h[s], 1u);
        }
    }
    __syncthreads();
    u32 v0 = h[tid];       if (v0) atomicAdd(&g_counts[tid], v0);
    u32 v1 = h[tid + 256]; if (v1) atomicAdd(&g_counts[tid + 256], v1);
}

__global__ void scan_kernel(const u32* __restrict__ counts,
                            u32* __restrict__ offsets,
                            u32* __restrict__ cursor) {
    // <<<1,512>>> exclusive scan over 512 bins (Hillis-Steele, ping-pong)
    __shared__ u32 A[NGR], B[NGR];
    int t = threadIdx.x;
    u32 c = counts[t];
    A[t] = c;
    __syncthreads();
    u32* src = A; u32* dst = B;
    for (int off = 1; off < NGR; off <<= 1) {
        u32 v = src[t];
        if (t >= off) v += src[t - off];
        dst[t] = v;
        __syncthreads();
        u32* tmp = src; src = dst; dst = tmp;
    }
    u32 exc = src[t] - c;
    offsets[t] = exc;
    cursor[t]  = exc;
}

__global__ void scatter_kernel(const u16* __restrict__ seg,
                               u32* __restrict__ cursor,
                               u32* __restrict__ sorted, int E) {
    __shared__ u32 h[NGR];
    __shared__ u32 bs[NGR];
    int tid = threadIdx.x;
    h[tid] = 0u; h[tid + 256] = 0u;
    __syncthreads();
    int base = blockIdx.x * EPB + tid;
    u16 segs[ITEMS];
    u16 ranks[ITEMS];
#pragma unroll
    for (int i = 0; i < ITEMS; ++i) {
        int e = base + i * HT;
        if (e < E) {
            int s = seg[e];
            segs[i]  = (u16)s;
            ranks[i] = (u16)atomicAdd(&h[s], 1u);  // rank < EPB fits u16
        }
    }
    __syncthreads();
    u32 v0 = h[tid];       if (v0) bs[tid]       = atomicAdd(&cursor[tid], v0);
    u32 v1 = h[tid + 256]; if (v1) bs[tid + 256] = atomicAdd(&cursor[tid + 256], v1);
    __syncthreads();
#pragma unroll
    for (int i = 0; i < ITEMS; ++i) {
        int e = base + i * HT;
        if (e < E) {
            sorted[bs[segs[i]] + ranks[i]] = (u32)e;
        }
    }
}

// Lean gather-reduce: 4 KB LDS, 8 blocks/CU, SPLIT blocks per graph.
__launch_bounds__(256, 8)
__global__ void reduce_kernel(const float* __restrict__ edge_attr,
                              const u32* __restrict__ sorted,
                              const u32* __restrict__ counts,
                              const u32* __restrict__ offsets,
                              float* __restrict__ partial) {
    __shared__ float red[8 * NF];   // 4 KB
    int tid = threadIdx.x;
    int g   = blockIdx.x >> 3;      // graph
    int s   = blockIdx.x & (SPLIT - 1);
    u32 off = offsets[g];
    u32 cnt = counts[g];
    u32 chunk = (cnt + SPLIT - 1) / SPLIT;
    u32 start = (u32)s * chunk;
    u32 end   = min(cnt, start + chunk);

    int row  = tid >> 5;    // 0..7
    int lane = tid & 31;    // float4 index within the 128-f row

    float4 a0 = make_float4(0.f, 0.f, 0.f, 0.f);
    float4 a1 = a0, a2 = a0, a3 = a0;

    u32 j = start + (u32)row;
    // 4-deep ILP: 4 independent row gathers in flight per thread
    for (; j + 24 < end; j += 32) {
        u32 e0 = sorted[off + j];
        u32 e1 = sorted[off + j + 8];
        u32 e2 = sorted[off + j + 16];
        u32 e3 = sorted[off + j + 24];
        float4 v0 = ((const float4*)(edge_attr + (size_t)e0 * NF))[lane];
        float4 v1 = ((const float4*)(edge_attr + (size_t)e1 * NF))[lane];
        float4 v2 = ((const float4*)(edge_attr + (size_t)e2 * NF))[lane];
        float4 v3 = ((const float4*)(edge_attr + (size_t)e3 * NF))[lane];
        a0.x += v0.x; a0.y += v0.y; a0.z += v0.z; a0.w += v0.w;
        a1.x += v1.x; a1.y += v1.y; a1.z += v1.z; a1.w += v1.w;
        a2.x += v2.x; a2.y += v2.y; a2.z += v2.z; a2.w += v2.w;
        a3.x += v3.x; a3.y += v3.y; a3.z += v3.z; a3.w += v3.w;
    }
    for (; j < end; j += 8) {
        u32 e = sorted[off + j];
        float4 v = ((const float4*)(edge_attr + (size_t)e * NF))[lane];
        a0.x += v.x; a0.y += v.y; a0.z += v.z; a0.w += v.w;
    }
    a0.x += a1.x + a2.x + a3.x;
    a0.y += a1.y + a2.y + a3.y;
    a0.z += a1.z + a2.z + a3.z;
    a0.w += a1.w + a2.w + a3.w;
    ((float4*)red)[row * 32 + lane] = a0;
    __syncthreads();

    if (tid < NF) {
        float v = 0.f;
#pragma unroll
        for (int r = 0; r < 8; ++r) v += red[r * NF + tid];
        partial[(size_t)blockIdx.x * NF + tid] = v;
    }
}

// Tiny finalize: mean + 2-layer MLP. Weights stream from L2 (hot after block 0).
__global__ void final_kernel(const float* __restrict__ partial,
                             const u32* __restrict__ counts,
                             const float* __restrict__ u,
                             const float* __restrict__ W1,
                             const float* __restrict__ b1,
                             const float* __restrict__ W2,
                             const float* __restrict__ b2,
                             float* __restrict__ out) {
    __shared__ float vin[IN1];
    __shared__ float hv[HID];
    int b = blockIdx.x, t = threadIdx.x;
    if (t < NF) {
        float s = 0.f;
#pragma unroll
        for (int r = 0; r < SPLIT; ++r)
            s += partial[(size_t)(b * SPLIT + r) * NF + t];
        vin[GF + t] = s / fmaxf((float)counts[b], 1.0f);   // scatter-mean
    }
    if (t < GF) vin[t] = u[b * GF + t];
    __syncthreads();
    if (t < HID) {
        float acc = b1[t];
#pragma unroll
        for (int k = 0; k < IN1; ++k) acc += vin[k] * W1[k * HID + t];
        hv[t] = fmaxf(acc, 0.0f);
    }
    __syncthreads();
    if (t < GF) {
        float acc = b2[t];
#pragma unroll
        for (int k = 0; k < HID; ++k) acc += hv[k] * W2[k * GF + t];
        out[b * GF + t] = acc;
    }
}

extern "C" void kernel_launch(void* const* d_in, const int* in_sizes, int n_in,
                              void* d_out, int out_size, void* d_ws, size_t ws_size,
                              hipStream_t stream) {
    // inputs: 0:x(unused) 1:edge_index[2,E] 2:edge_attr[E,128] 3:u[512,64]
    //         4:batch[50000] 5:W1[192,64] 6:b1[64] 7:W2[64,64] 8:b2[64]
    const int*   ei        = (const int*)d_in[1];
    const float* edge_attr = (const float*)d_in[2];
    const float* u         = (const float*)d_in[3];
    const int*   batch     = (const int*)d_in[4];
    const float* W1        = (const float*)d_in[5];
    const float* b1        = (const float*)d_in[6];
    const float* W2        = (const float*)d_in[7];
    const float* b2        = (const float*)d_in[8];
    float*       out       = (float*)d_out;

    const int E = in_sizes[1] / 2;
    const int* ei0 = ei;   // row 0 of edge_index

    // workspace layout (floats/u32 are 4B-aligned; seg u16 after sorted):
    // sorted[E] u32 | partial[512*SPLIT*128] f32 | counts[512] | offsets[512]
    // | cursor[512] | seg[E] u16
    u32*   sorted  = (u32*)d_ws;
    float* partial = (float*)(sorted + E);
    u32*   counts  = (u32*)(partial + (size_t)NGR * SPLIT * NF);
    u32*   offsets = counts + NGR;
    u32*   cursor  = offsets + NGR;
    u16*   seg     = (u16*)(cursor + NGR);

    const int nblocks = (E + EPB - 1) / EPB;

    zero_counts_kernel<<<1, NGR, 0, stream>>>(counts);
    hist_kernel<<<nblocks, HT, 0, stream>>>(ei0, batch, counts, seg, E);
    scan_kernel<<<1, NGR, 0, stream>>>(counts, offsets, cursor);
    scatter_kernel<<<nblocks, HT, 0, stream>>>(seg, cursor, sorted, E);
    reduce_kernel<<<NGR * SPLIT, 256, 0, stream>>>(edge_attr, sorted, counts,
                                                   offsets, partial);
    final_kernel<<<NGR, 128, 0, stream>>>(partial, counts, u, W1, b1, W2, b2, out);
}